// Round 1
// baseline (1150.043 us; speedup 1.0000x reference)
//
#include <hip/hip_runtime.h>
#include <hip/hip_bf16.h>

#define NH 16
#define DH 64
#define DM 1024
#define NC 2048
#define BT 2
#define MROWS (BT * NC)  // 4096

// ---------------------------------------------------------------------------
// Tiled fp32 GEMM: C[M,N] = A[M,K] @ B[K,N] (+ bias row-broadcast)
// 64x64 tile, BK=16, 256 threads, 4x4 microtile per thread.
// LDS padded to 68 floats/row: all hot reads broadcast or 2-way (free).
// ---------------------------------------------------------------------------
__global__ __launch_bounds__(256) void gemm64(const float* __restrict__ A,
                                              const float* __restrict__ B,
                                              const float* __restrict__ bias,
                                              float* __restrict__ C,
                                              int M, int N, int K)
{
    __shared__ float As[16][68];  // As[k][m]
    __shared__ float Bs[16][68];  // Bs[k][n]
    const int t  = threadIdx.x;
    const int bm = blockIdx.y << 6;
    const int bn = blockIdx.x << 6;
    const int tm = (t >> 4) << 2;
    const int tn = (t & 15) << 2;
    const int ar = t >> 2;          // 0..63 (A row in tile)
    const int ac = (t & 3) << 2;    // 0,4,8,12 (A k-col)
    const int br = t >> 4;          // 0..15 (B k-row)

    float acc[4][4] = {};
    const float* Ap = A + (size_t)(bm + ar) * K + ac;
    const float* Bp = B + (size_t)br * N + bn + tn;

    for (int k0 = 0; k0 < K; k0 += 16) {
        float4 av = *(const float4*)(Ap + k0);
        float4 bv = *(const float4*)(Bp + (size_t)k0 * N);
        As[ac + 0][ar] = av.x;
        As[ac + 1][ar] = av.y;
        As[ac + 2][ar] = av.z;
        As[ac + 3][ar] = av.w;
        *(float4*)&Bs[br][tn] = bv;
        __syncthreads();
        #pragma unroll
        for (int kk = 0; kk < 16; ++kk) {
            float4 a4 = *(const float4*)&As[kk][tm];
            float4 b4 = *(const float4*)&Bs[kk][tn];
            float aa[4] = {a4.x, a4.y, a4.z, a4.w};
            float bb[4] = {b4.x, b4.y, b4.z, b4.w};
            #pragma unroll
            for (int i = 0; i < 4; ++i)
                #pragma unroll
                for (int j = 0; j < 4; ++j)
                    acc[i][j] += aa[i] * bb[j];
        }
        __syncthreads();
    }

    float4 bv4 = {0.f, 0.f, 0.f, 0.f};
    if (bias) bv4 = *(const float4*)&bias[bn + tn];
    #pragma unroll
    for (int i = 0; i < 4; ++i) {
        float4 r;
        r.x = acc[i][0] + bv4.x;
        r.y = acc[i][1] + bv4.y;
        r.z = acc[i][2] + bv4.z;
        r.w = acc[i][3] + bv4.w;
        *(float4*)&C[(size_t)(bm + tm + i) * N + bn + tn] = r;
    }
}

// ---------------------------------------------------------------------------
// Flash-style fp32 attention with half-causal mask.
// Q/K/V stored as [MROWS][DM] ([b*NC + n][h*DH + d]).
// Block: one (b,h) x 64 q-rows. 256 threads: thread = 4*r_row + cg.
// S-phase: thread owns cols c = cg + 4*cc (cc=0..15) -> conflict-free K reads.
// PV-phase: thread owns dims d = cg*16 .. cg*16+15 -> 2-way (free) V reads.
// Top-half q-tiles (qt<16): 16 dense KV tiles. Bottom: qt+1 tiles, mask only
// on the diagonal tile.
// ---------------------------------------------------------------------------
__global__ __launch_bounds__(256) void attn64(const float* __restrict__ Qg,
                                              const float* __restrict__ Kg,
                                              const float* __restrict__ Vg,
                                              float* __restrict__ Og)
{
    __shared__ float Qs[64][68];
    __shared__ float Ks[64][68];
    __shared__ float Vs[64][68];
    __shared__ float Ps[64][68];
    const int t  = threadIdx.x;
    const int qt = blockIdx.x;       // 0..31
    const int bh = blockIdx.y;       // b*16 + h
    const int b  = bh >> 4;
    const int h  = bh & 15;
    const int r  = t >> 2;           // q-row in tile
    const int cg = t & 3;

    const size_t hb    = (size_t)b * NC * DM + (size_t)h * DH;
    const size_t qbase = hb + (size_t)(qt << 6) * DM;

    // Load Q tile, pre-scaled by 1/sqrt(64) = 0.125
    #pragma unroll
    for (int j = 0; j < 4; ++j) {
        int idx = (j << 8) + t;        // 0..1023 float4 index
        int rr  = idx >> 4;
        int c4  = (idx & 15) << 2;
        float4 v = *(const float4*)(Qg + qbase + (size_t)rr * DM + c4);
        v.x *= 0.125f; v.y *= 0.125f; v.z *= 0.125f; v.w *= 0.125f;
        *(float4*)&Qs[rr][c4] = v;
    }

    float m = -1e30f, l = 0.f;
    float4 o4[4] = {};
    const int nkv = (qt < 16) ? 16 : (qt + 1);

    for (int kvt = 0; kvt < nkv; ++kvt) {
        const size_t kb = hb + (size_t)(kvt << 6) * DM;
        #pragma unroll
        for (int j = 0; j < 4; ++j) {
            int idx = (j << 8) + t;
            int rr  = idx >> 4;
            int c4  = (idx & 15) << 2;
            *(float4*)&Ks[rr][c4] = *(const float4*)(Kg + kb + (size_t)rr * DM + c4);
            *(float4*)&Vs[rr][c4] = *(const float4*)(Vg + kb + (size_t)rr * DM + c4);
        }
        __syncthreads();  // (A) K,V visible

        // S = Q K^T for this thread's 16 columns
        float p[16];
        #pragma unroll
        for (int cc = 0; cc < 16; ++cc) p[cc] = 0.f;
        for (int d4 = 0; d4 < 16; ++d4) {
            float4 q4 = *(const float4*)&Qs[r][d4 << 2];
            #pragma unroll
            for (int cc = 0; cc < 16; ++cc) {
                float4 k4 = *(const float4*)&Ks[cg + (cc << 2)][d4 << 2];
                p[cc] += q4.x * k4.x + q4.y * k4.y + q4.z * k4.z + q4.w * k4.w;
            }
        }

        // mask only needed on the diagonal tile of the causal (bottom) half
        if (qt >= 16 && kvt == qt) {
            #pragma unroll
            for (int cc = 0; cc < 16; ++cc)
                if (cg + (cc << 2) > r) p[cc] = -1e30f;
        }

        // online softmax (row stats shared by the 4 lanes of each row)
        float tmax = p[0];
        #pragma unroll
        for (int cc = 1; cc < 16; ++cc) tmax = fmaxf(tmax, p[cc]);
        tmax = fmaxf(tmax, __shfl_xor(tmax, 1));
        tmax = fmaxf(tmax, __shfl_xor(tmax, 2));
        const float mnew = fmaxf(m, tmax);
        const float corr = __expf(m - mnew);
        float rs = 0.f;
        #pragma unroll
        for (int cc = 0; cc < 16; ++cc) {
            p[cc] = __expf(p[cc] - mnew);
            rs += p[cc];
        }
        rs += __shfl_xor(rs, 1);
        rs += __shfl_xor(rs, 2);
        l = l * corr + rs;
        m = mnew;

        #pragma unroll
        for (int cc = 0; cc < 16; ++cc) Ps[r][cg + (cc << 2)] = p[cc];
        __syncthreads();  // (B) P visible

        #pragma unroll
        for (int j4 = 0; j4 < 4; ++j4) {
            o4[j4].x *= corr; o4[j4].y *= corr;
            o4[j4].z *= corr; o4[j4].w *= corr;
        }
        for (int c = 0; c < 64; ++c) {
            float pv = Ps[r][c];
            #pragma unroll
            for (int j4 = 0; j4 < 4; ++j4) {
                float4 v4 = *(const float4*)&Vs[c][(cg << 4) + (j4 << 2)];
                o4[j4].x += pv * v4.x;
                o4[j4].y += pv * v4.y;
                o4[j4].z += pv * v4.z;
                o4[j4].w += pv * v4.w;
            }
        }
        __syncthreads();  // (C) all reads done, next iter may overwrite
    }

    // normalize and write out via LDS for coalescing (reuse Qs)
    const float inv = 1.f / l;
    #pragma unroll
    for (int j4 = 0; j4 < 4; ++j4) {
        float4 v = o4[j4];
        v.x *= inv; v.y *= inv; v.z *= inv; v.w *= inv;
        *(float4*)&Qs[r][(cg << 4) + (j4 << 2)] = v;
    }
    __syncthreads();
    #pragma unroll
    for (int j = 0; j < 4; ++j) {
        int idx = (j << 8) + t;
        int rr  = idx >> 4;
        int c4  = (idx & 15) << 2;
        *(float4*)(Og + qbase + (size_t)rr * DM + c4) = *(const float4*)&Qs[rr][c4];
    }
}

// ---------------------------------------------------------------------------
extern "C" void kernel_launch(void* const* d_in, const int* in_sizes, int n_in,
                              void* d_out, int out_size, void* d_ws, size_t ws_size,
                              hipStream_t stream)
{
    const float* x  = (const float*)d_in[0];
    const float* Wq = (const float*)d_in[1];
    const float* bq = (const float*)d_in[2];
    const float* Wk = (const float*)d_in[3];
    const float* bk = (const float*)d_in[4];
    const float* Wv = (const float*)d_in[5];
    const float* bv = (const float*)d_in[6];
    const float* Wo = (const float*)d_in[7];
    float* out = (float*)d_out;

    char* ws = (char*)d_ws;
    const size_t sz = (size_t)MROWS * DM * sizeof(float);  // 16.78 MB
    float* q  = (float*)(ws + 0 * sz);
    float* k  = (float*)(ws + 1 * sz);
    float* v  = (float*)(ws + 2 * sz);
    float* ao = (float*)(ws + 3 * sz);

    dim3 gg(DM / 64, MROWS / 64);  // (16, 64)
    gemm64<<<gg, 256, 0, stream>>>(x, Wq, bq, q, MROWS, DM, DM);
    gemm64<<<gg, 256, 0, stream>>>(x, Wk, bk, k, MROWS, DM, DM);
    gemm64<<<gg, 256, 0, stream>>>(x, Wv, bv, v, MROWS, DM, DM);
    attn64<<<dim3(32, 32), 256, 0, stream>>>(q, k, v, ao);
    gemm64<<<gg, 256, 0, stream>>>(ao, Wo, nullptr, out, MROWS, DM, DM);
}

// Round 2
// 570.950 us; speedup vs baseline: 2.0143x; 2.0143x over previous
//
#include <hip/hip_runtime.h>
#include <hip/hip_bf16.h>

#define NH 16
#define DH 64
#define DM 1024
#define NC 2048
#define MROWS 4096
#define QB 128
#define KVT 64

typedef __attribute__((ext_vector_type(8))) short short8;
typedef __attribute__((ext_vector_type(16))) float f32x16;
typedef __attribute__((ext_vector_type(4))) unsigned int uint4e;

__device__ __forceinline__ unsigned pkbf16(float a, float b) {
    unsigned r;
    asm("v_cvt_pk_bf16_f32 %0, %1, %2" : "=v"(r) : "v"(a), "v"(b));
    return r;
}

__device__ __forceinline__ f32x16 fzero() {
    f32x16 r;
    #pragma unroll
    for (int i = 0; i < 16; ++i) r[i] = 0.f;
    return r;
}

__device__ __forceinline__ short8 mk8(unsigned w0, unsigned w1, unsigned w2, unsigned w3) {
    uint4e u = {w0, w1, w2, w3};
    return __builtin_bit_cast(short8, u);
}

// ---------------------------------------------------------------------------
// fp32 GEMM (unchanged from R1): C = A@B (+bias). 64x64 tile, BK=16.
// ---------------------------------------------------------------------------
__global__ __launch_bounds__(256) void gemm64(const float* __restrict__ A,
                                              const float* __restrict__ B,
                                              const float* __restrict__ bias,
                                              float* __restrict__ C,
                                              int M, int N, int K)
{
    __shared__ float As[16][68];
    __shared__ float Bs[16][68];
    const int t  = threadIdx.x;
    const int bm = blockIdx.y << 6;
    const int bn = blockIdx.x << 6;
    const int tm = (t >> 4) << 2;
    const int tn = (t & 15) << 2;
    const int ar = t >> 2;
    const int ac = (t & 3) << 2;
    const int br = t >> 4;

    float acc[4][4] = {};
    const float* Ap = A + (size_t)(bm + ar) * K + ac;
    const float* Bp = B + (size_t)br * N + bn + tn;

    for (int k0 = 0; k0 < K; k0 += 16) {
        float4 av = *(const float4*)(Ap + k0);
        float4 bv = *(const float4*)(Bp + (size_t)k0 * N);
        As[ac + 0][ar] = av.x;
        As[ac + 1][ar] = av.y;
        As[ac + 2][ar] = av.z;
        As[ac + 3][ar] = av.w;
        *(float4*)&Bs[br][tn] = bv;
        __syncthreads();
        #pragma unroll
        for (int kk = 0; kk < 16; ++kk) {
            float4 a4 = *(const float4*)&As[kk][tm];
            float4 b4 = *(const float4*)&Bs[kk][tn];
            float aa[4] = {a4.x, a4.y, a4.z, a4.w};
            float bb[4] = {b4.x, b4.y, b4.z, b4.w};
            #pragma unroll
            for (int i = 0; i < 4; ++i)
                #pragma unroll
                for (int j = 0; j < 4; ++j)
                    acc[i][j] += aa[i] * bb[j];
        }
        __syncthreads();
    }

    float4 bv4 = {0.f, 0.f, 0.f, 0.f};
    if (bias) bv4 = *(const float4*)&bias[bn + tn];
    #pragma unroll
    for (int i = 0; i < 4; ++i) {
        float4 r;
        r.x = acc[i][0] + bv4.x;
        r.y = acc[i][1] + bv4.y;
        r.z = acc[i][2] + bv4.z;
        r.w = acc[i][3] + bv4.w;
        *(float4*)&C[(size_t)(bm + tm + i) * N + bn + tn] = r;
    }
}

// ---------------------------------------------------------------------------
// bf16-MFMA flash attention, half-causal mask.
// Block: (qt, bh) = 128 q-rows of one (b,h). 4 waves x 32 q-rows each.
// S^T = K.Q^T via mfma_32x32x16_bf16 (lane owns q-row = lane&31), online
// softmax per-lane + one shfl_xor(32); O^T = V^T.P^T accumulated in f32.
// K staged row-major bf16 [64][68]; V staged transposed Vt[d][k] bf16.
// ---------------------------------------------------------------------------
__global__ __launch_bounds__(256) void attn_mfma(const float* __restrict__ Qg,
                                                 const float* __restrict__ Kg,
                                                 const float* __restrict__ Vg,
                                                 float* __restrict__ Og)
{
    __shared__ short SM[2][64][68];  // [0]=K bf16 rows, [1]=V^T bf16
    const int t   = threadIdx.x;
    const int w   = t >> 6;
    const int l   = t & 63;
    const int l31 = l & 31;
    const int hi  = l >> 5;
    const int qt  = blockIdx.x;      // 0..15
    const int bh  = blockIdx.y;      // 0..31
    const int b   = bh >> 4;
    const int h   = bh & 15;

    const int qb = qt * QB;
    const int wq = qb + w * 32;
    const size_t rb0 = (size_t)b * NC;
    const int hd = h * DH;

    // ---- Q fragments in registers, pre-scaled by 1/sqrt(64) ----
    const float* qp = Qg + (rb0 + wq + l31) * DM + hd + hi * 8;
    short8 fq[4];
    #pragma unroll
    for (int c = 0; c < 4; ++c) {
        float4 x0 = *(const float4*)(qp + c * 16);
        float4 x1 = *(const float4*)(qp + c * 16 + 4);
        fq[c] = mk8(pkbf16(x0.x * 0.125f, x0.y * 0.125f),
                    pkbf16(x0.z * 0.125f, x0.w * 0.125f),
                    pkbf16(x1.x * 0.125f, x1.y * 0.125f),
                    pkbf16(x1.z * 0.125f, x1.w * 0.125f));
    }

    f32x16 o0 = fzero(), o1 = fzero();
    float mrun = -1e30f, lrun = 0.f;
    const bool bottom = (qb >= NC / 2);
    const int nkv = bottom ? (2 * qt + 2) : 16;
    const int srow = t & 63;
    const int sseg = t >> 6;

    for (int it = 0; it < nkv; ++it) {
        const int kb = it * KVT;
        // ---- stage K (row-major) and V (transposed) as bf16 ----
        {
            const float* kp = Kg + (rb0 + kb + srow) * DM + hd + sseg * 16;
            const float* vp = Vg + (rb0 + kb + srow) * DM + hd + sseg * 16;
            float ka[16], va[16];
            *(float4*)&ka[0]  = *(const float4*)(kp);
            *(float4*)&ka[4]  = *(const float4*)(kp + 4);
            *(float4*)&ka[8]  = *(const float4*)(kp + 8);
            *(float4*)&ka[12] = *(const float4*)(kp + 12);
            *(float4*)&va[0]  = *(const float4*)(vp);
            *(float4*)&va[4]  = *(const float4*)(vp + 4);
            *(float4*)&va[8]  = *(const float4*)(vp + 8);
            *(float4*)&va[12] = *(const float4*)(vp + 12);
            uint2 kw;
            kw.x = pkbf16(ka[0], ka[1]);   kw.y = pkbf16(ka[2], ka[3]);
            *(uint2*)&SM[0][srow][sseg * 16]      = kw;
            kw.x = pkbf16(ka[4], ka[5]);   kw.y = pkbf16(ka[6], ka[7]);
            *(uint2*)&SM[0][srow][sseg * 16 + 4]  = kw;
            kw.x = pkbf16(ka[8], ka[9]);   kw.y = pkbf16(ka[10], ka[11]);
            *(uint2*)&SM[0][srow][sseg * 16 + 8]  = kw;
            kw.x = pkbf16(ka[12], ka[13]); kw.y = pkbf16(ka[14], ka[15]);
            *(uint2*)&SM[0][srow][sseg * 16 + 12] = kw;
            #pragma unroll
            for (int j = 0; j < 16; ++j)
                SM[1][sseg * 16 + j][srow] = (short)(pkbf16(va[j], va[j]) & 0xffffu);
        }
        __syncthreads();

        const bool active = bottom ? (kb <= wq + 31) : true;
        if (active) {
            // ---- S^T = K . Q^T (two 32-row k-tiles, 4 d-chunks) ----
            f32x16 s0 = fzero(), s1 = fzero();
            #pragma unroll
            for (int c = 0; c < 4; ++c) {
                const int off = c * 16 + hi * 8;
                uint2 a0 = *(const uint2*)&SM[0][l31][off];
                uint2 a1 = *(const uint2*)&SM[0][l31][off + 4];
                uint2 b0 = *(const uint2*)&SM[0][32 + l31][off];
                uint2 b1 = *(const uint2*)&SM[0][32 + l31][off + 4];
                s0 = __builtin_amdgcn_mfma_f32_32x32x16_bf16(
                        mk8(a0.x, a0.y, a1.x, a1.y), fq[c], s0, 0, 0, 0);
                s1 = __builtin_amdgcn_mfma_f32_32x32x16_bf16(
                        mk8(b0.x, b0.y, b1.x, b1.y), fq[c], s1, 0, 0, 0);
            }
            // ---- causal mask (diagonal-crossing tiles of bottom half only) ----
            if (bottom && (kb + KVT - 1 > wq)) {
                const int qg = wq + l31;
                #pragma unroll
                for (int r = 0; r < 16; ++r) {
                    const int kk = (r & 3) + 8 * (r >> 2) + 4 * hi;
                    if (kb + kk > qg)      s0[r] = -1e30f;
                    if (kb + 32 + kk > qg) s1[r] = -1e30f;
                }
            }
            // ---- online softmax: lane owns q-row = l31 (partner lane l^32 same row) ----
            float pm = s0[0];
            #pragma unroll
            for (int r = 1; r < 16; ++r) pm = fmaxf(pm, s0[r]);
            #pragma unroll
            for (int r = 0; r < 16; ++r) pm = fmaxf(pm, s1[r]);
            pm = fmaxf(pm, __shfl_xor(pm, 32));
            const float mnew = fmaxf(mrun, pm);
            const float corr = __expf(mrun - mnew);
            float rs = 0.f;
            #pragma unroll
            for (int r = 0; r < 16; ++r) { s0[r] = __expf(s0[r] - mnew); rs += s0[r]; }
            #pragma unroll
            for (int r = 0; r < 16; ++r) { s1[r] = __expf(s1[r] - mnew); rs += s1[r]; }
            rs += __shfl_xor(rs, 32);
            lrun = lrun * corr + rs;
            mrun = mnew;
            #pragma unroll
            for (int i = 0; i < 16; ++i) { o0[i] *= corr; o1[i] *= corr; }
            // ---- P -> bf16 B-frags (cvt_pk + xor32 exchange), PV accumulate ----
            #pragma unroll
            for (int kc = 0; kc < 4; ++kc) {
                const f32x16 src = (kc < 2) ? s0 : s1;
                const int rbase = (kc & 1) * 8;
                unsigned A01 = pkbf16(src[rbase + 0], src[rbase + 1]);
                unsigned A23 = pkbf16(src[rbase + 2], src[rbase + 3]);
                unsigned A45 = pkbf16(src[rbase + 4], src[rbase + 5]);
                unsigned A67 = pkbf16(src[rbase + 6], src[rbase + 7]);
                unsigned s01 = (unsigned)__shfl_xor((int)A01, 32);
                unsigned s23 = (unsigned)__shfl_xor((int)A23, 32);
                unsigned s45 = (unsigned)__shfl_xor((int)A45, 32);
                unsigned s67 = (unsigned)__shfl_xor((int)A67, 32);
                short8 fp = hi ? mk8(s45, s67, A45, A67)
                               : mk8(A01, A23, s01, s23);
                const int voff = kc * 16 + hi * 8;
                uint2 va0 = *(const uint2*)&SM[1][l31][voff];
                uint2 va1 = *(const uint2*)&SM[1][l31][voff + 4];
                uint2 vb0 = *(const uint2*)&SM[1][32 + l31][voff];
                uint2 vb1 = *(const uint2*)&SM[1][32 + l31][voff + 4];
                o0 = __builtin_amdgcn_mfma_f32_32x32x16_bf16(
                        mk8(va0.x, va0.y, va1.x, va1.y), fp, o0, 0, 0, 0);
                o1 = __builtin_amdgcn_mfma_f32_32x32x16_bf16(
                        mk8(vb0.x, vb0.y, vb1.x, vb1.y), fp, o1, 0, 0, 0);
            }
        }
        __syncthreads();
    }

    // ---- epilogue: normalize, bounce O^T through LDS, coalesced store ----
    const float inv = 1.f / lrun;
    float* obuf = (float*)&SM[0][0][0];   // 4352 floats total
    for (int round = 0; round < 2; ++round) {
        if ((w >> 1) == round) {
            float* reg = obuf + (w & 1) * 2176 + l31 * 68;
            #pragma unroll
            for (int r = 0; r < 16; ++r) {
                const int dd = (r & 3) + 8 * (r >> 2) + 4 * hi;
                reg[dd]      = o0[r] * inv;
                reg[dd + 32] = o1[r] * inv;
            }
        }
        __syncthreads();
        {
            const int row = t & 63, seg = t >> 6;
            const float* src = obuf + (row >> 5) * 2176 + (row & 31) * 68 + seg * 16;
            float4 y0 = *(const float4*)(src);
            float4 y1 = *(const float4*)(src + 4);
            float4 y2 = *(const float4*)(src + 8);
            float4 y3 = *(const float4*)(src + 12);
            float* dst = Og + (rb0 + qb + round * 64 + row) * DM + hd + seg * 16;
            *(float4*)(dst)      = y0;
            *(float4*)(dst + 4)  = y1;
            *(float4*)(dst + 8)  = y2;
            *(float4*)(dst + 12) = y3;
        }
        __syncthreads();
    }
}

// ---------------------------------------------------------------------------
extern "C" void kernel_launch(void* const* d_in, const int* in_sizes, int n_in,
                              void* d_out, int out_size, void* d_ws, size_t ws_size,
                              hipStream_t stream)
{
    const float* x  = (const float*)d_in[0];
    const float* Wq = (const float*)d_in[1];
    const float* bq = (const float*)d_in[2];
    const float* Wk = (const float*)d_in[3];
    const float* bk = (const float*)d_in[4];
    const float* Wv = (const float*)d_in[5];
    const float* bv = (const float*)d_in[6];
    const float* Wo = (const float*)d_in[7];
    float* out = (float*)d_out;

    char* ws = (char*)d_ws;
    const size_t sz = (size_t)MROWS * DM * sizeof(float);
    float* q  = (float*)(ws + 0 * sz);
    float* k  = (float*)(ws + 1 * sz);
    float* v  = (float*)(ws + 2 * sz);
    float* ao = (float*)(ws + 3 * sz);

    dim3 gg(DM / 64, MROWS / 64);
    gemm64<<<gg, 256, 0, stream>>>(x, Wq, bq, q, MROWS, DM, DM);
    gemm64<<<gg, 256, 0, stream>>>(x, Wk, bk, k, MROWS, DM, DM);
    gemm64<<<gg, 256, 0, stream>>>(x, Wv, bv, v, MROWS, DM, DM);
    attn_mfma<<<dim3(16, 32), 256, 0, stream>>>(q, k, v, ao);
    gemm64<<<gg, 256, 0, stream>>>(ao, Wo, nullptr, out, MROWS, DM, DM);
}

// Round 3
// 197.717 us; speedup vs baseline: 5.8166x; 2.8877x over previous
//
#include <hip/hip_runtime.h>
#include <hip/hip_bf16.h>

#define NH 16
#define DH 64
#define DM 1024
#define NC 2048
#define MROWS 4096
#define QB 128
#define KVT 64

typedef __attribute__((ext_vector_type(8))) short short8;
typedef __attribute__((ext_vector_type(4))) float f32x4;
typedef __attribute__((ext_vector_type(16))) float f32x16;
typedef __attribute__((ext_vector_type(4))) unsigned int uint4e;

__device__ __forceinline__ unsigned pkbf16(float a, float b) {
    unsigned r;
    asm("v_cvt_pk_bf16_f32 %0, %1, %2" : "=v"(r) : "v"(a), "v"(b));
    return r;
}
__device__ __forceinline__ unsigned short f2bf(float x) {
    return (unsigned short)(pkbf16(x, x) & 0xffffu);
}
__device__ __forceinline__ f32x16 fzero16() {
    f32x16 r;
    #pragma unroll
    for (int i = 0; i < 16; ++i) r[i] = 0.f;
    return r;
}
__device__ __forceinline__ short8 mk8(unsigned w0, unsigned w1, unsigned w2, unsigned w3) {
    uint4e u = {w0, w1, w2, w3};
    return __builtin_bit_cast(short8, u);
}

// ---------------------------------------------------------------------------
// fp32 -> bf16 elementwise convert (8 elems/thread)
// ---------------------------------------------------------------------------
__global__ __launch_bounds__(256) void cvt_x(const float* __restrict__ in,
                                             unsigned short* __restrict__ out, int n8)
{
    int i = blockIdx.x * 256 + threadIdx.x;
    if (i >= n8) return;
    const float4 a = ((const float4*)in)[i * 2];
    const float4 b = ((const float4*)in)[i * 2 + 1];
    uint4e u = {pkbf16(a.x, a.y), pkbf16(a.z, a.w), pkbf16(b.x, b.y), pkbf16(b.z, b.w)};
    ((uint4e*)out)[i] = u;
}

// ---------------------------------------------------------------------------
// W[K][N] fp32 -> Wt[N][K] bf16 (transpose + convert), 64x64 tiles
// ---------------------------------------------------------------------------
__global__ __launch_bounds__(256) void cvt_wT(const float* __restrict__ W,
                                              unsigned short* __restrict__ Wt,
                                              int Kd, int Nd)
{
    __shared__ unsigned short T[64][72];
    const int t = threadIdx.x;
    const int r = t >> 2, s = t & 3;
    const int bi = blockIdx.y;  // k block
    const int bj = blockIdx.x;  // n block
    const float* src = W + (size_t)(bi * 64 + r) * Nd + bj * 64 + s * 16;
    float4 f0 = ((const float4*)src)[0];
    float4 f1 = ((const float4*)src)[1];
    float4 f2 = ((const float4*)src)[2];
    float4 f3 = ((const float4*)src)[3];
    uint2 u;
    u.x = pkbf16(f0.x, f0.y); u.y = pkbf16(f0.z, f0.w); *(uint2*)&T[r][s * 16]      = u;
    u.x = pkbf16(f1.x, f1.y); u.y = pkbf16(f1.z, f1.w); *(uint2*)&T[r][s * 16 + 4]  = u;
    u.x = pkbf16(f2.x, f2.y); u.y = pkbf16(f2.z, f2.w); *(uint2*)&T[r][s * 16 + 8]  = u;
    u.x = pkbf16(f3.x, f3.y); u.y = pkbf16(f3.z, f3.w); *(uint2*)&T[r][s * 16 + 12] = u;
    __syncthreads();
    unsigned short vals[16];
    #pragma unroll
    for (int j = 0; j < 16; ++j) vals[j] = T[s * 16 + j][r];
    unsigned short* dst = Wt + (size_t)(bj * 64 + r) * Kd + bi * 64 + s * 16;
    *(short8*)(dst)     = *(short8*)&vals[0];
    *(short8*)(dst + 8) = *(short8*)&vals[8];
}

// ---------------------------------------------------------------------------
// bf16 MFMA GEMM: C[M,N] = A[M,K] @ Bt[N,K]^T (+bias)*scale
// 128x128 tile, BK=32, 256 threads / 4 waves (2x2), wave-tile 64x64,
// 16 x mfma_f32_16x16x32_bf16 per K-step. LDS [128][40] shorts: 2-way free.
// ---------------------------------------------------------------------------
__global__ __launch_bounds__(256) void gemm_bf16(const unsigned short* __restrict__ A,
                                                 const unsigned short* __restrict__ Bt,
                                                 const float* __restrict__ bias,
                                                 void* __restrict__ C,
                                                 int M, int Nd, int Kd,
                                                 float scale, int outBF16)
{
    __shared__ unsigned short As[128 * 40];
    __shared__ unsigned short Bs[128 * 40];
    const int t  = threadIdx.x;
    const int w  = t >> 6;
    const int l  = t & 63;
    const int wr = w >> 1, wc = w & 1;
    const int m0 = blockIdx.y << 7;
    const int n0 = blockIdx.x << 7;
    const int r0 = t >> 2;      // staging row 0..63
    const int ch = t & 3;       // staging k-chunk

    f32x4 acc[4][4] = {};
    short8 ra[2], rb[2];

    const int nkt = Kd >> 5;
    // prologue loads (kt=0)
    #pragma unroll
    for (int j = 0; j < 2; ++j) {
        ra[j] = *(const short8*)(A  + (size_t)(m0 + r0 + j * 64) * Kd + ch * 8);
        rb[j] = *(const short8*)(Bt + (size_t)(n0 + r0 + j * 64) * Kd + ch * 8);
    }

    for (int kt = 0; kt < nkt; ++kt) {
        #pragma unroll
        for (int j = 0; j < 2; ++j) {
            *(short8*)&As[(r0 + j * 64) * 40 + ch * 8] = ra[j];
            *(short8*)&Bs[(r0 + j * 64) * 40 + ch * 8] = rb[j];
        }
        __syncthreads();
        if (kt + 1 < nkt) {
            const int ko = (kt + 1) * 32;
            #pragma unroll
            for (int j = 0; j < 2; ++j) {
                ra[j] = *(const short8*)(A  + (size_t)(m0 + r0 + j * 64) * Kd + ko + ch * 8);
                rb[j] = *(const short8*)(Bt + (size_t)(n0 + r0 + j * 64) * Kd + ko + ch * 8);
            }
        }
        short8 af[4], bf_[4];
        #pragma unroll
        for (int mi = 0; mi < 4; ++mi)
            af[mi] = *(short8*)&As[(wr * 64 + mi * 16 + (l & 15)) * 40 + (l >> 4) * 8];
        #pragma unroll
        for (int ni = 0; ni < 4; ++ni)
            bf_[ni] = *(short8*)&Bs[(wc * 64 + ni * 16 + (l & 15)) * 40 + (l >> 4) * 8];
        #pragma unroll
        for (int mi = 0; mi < 4; ++mi)
            #pragma unroll
            for (int ni = 0; ni < 4; ++ni)
                acc[mi][ni] = __builtin_amdgcn_mfma_f32_16x16x32_bf16(
                                  af[mi], bf_[ni], acc[mi][ni], 0, 0, 0);
        __syncthreads();
    }

    float bv[4];
    #pragma unroll
    for (int ni = 0; ni < 4; ++ni)
        bv[ni] = bias ? bias[n0 + wc * 64 + ni * 16 + (l & 15)] : 0.f;

    #pragma unroll
    for (int mi = 0; mi < 4; ++mi)
        #pragma unroll
        for (int ni = 0; ni < 4; ++ni) {
            const int gcol = n0 + wc * 64 + ni * 16 + (l & 15);
            #pragma unroll
            for (int r = 0; r < 4; ++r) {
                const int grow = m0 + wr * 64 + mi * 16 + (l >> 4) * 4 + r;
                const float val = (acc[mi][ni][r] + bv[ni]) * scale;
                if (outBF16)
                    ((unsigned short*)C)[(size_t)grow * Nd + gcol] = f2bf(val);
                else
                    ((float*)C)[(size_t)grow * Nd + gcol] = val;
            }
        }
}

// ---------------------------------------------------------------------------
// bf16-MFMA flash attention, half-causal mask (structure validated in R2).
// Inputs/outputs bf16. Q pre-scaled by 0.125 (folded into projection GEMM).
// ---------------------------------------------------------------------------
__global__ __launch_bounds__(256) void attn_mfma(const unsigned short* __restrict__ Qg,
                                                 const unsigned short* __restrict__ Kg,
                                                 const unsigned short* __restrict__ Vg,
                                                 unsigned short* __restrict__ Og)
{
    __shared__ unsigned short SM[2][64][68];  // [0]=K rows, [1]=V^T
    const int t   = threadIdx.x;
    const int w   = t >> 6;
    const int l   = t & 63;
    const int l31 = l & 31;
    const int hi  = l >> 5;
    const int qt  = blockIdx.x;
    const int bh  = blockIdx.y;
    const int b   = bh >> 4;
    const int h   = bh & 15;

    const int qb = qt * QB;
    const int wq = qb + w * 32;
    const size_t rb0 = (size_t)b * NC;
    const int hd = h * DH;

    // Q fragments (already scaled)
    const unsigned short* qp = Qg + (rb0 + wq + l31) * DM + hd + hi * 8;
    short8 fq[4];
    #pragma unroll
    for (int c = 0; c < 4; ++c)
        fq[c] = *(const short8*)(qp + c * 16);

    f32x16 o0 = fzero16(), o1 = fzero16();
    float mrun = -1e30f, lrun = 0.f;
    const bool bottom = (qb >= NC / 2);
    const int nkv = bottom ? (2 * qt + 2) : 16;
    const int srow = t & 63;
    const int sseg = t >> 6;

    for (int it = 0; it < nkv; ++it) {
        const int kb = it * KVT;
        {
            const unsigned short* kp = Kg + (rb0 + kb + srow) * DM + hd + sseg * 16;
            const unsigned short* vp = Vg + (rb0 + kb + srow) * DM + hd + sseg * 16;
            short8 k0 = *(const short8*)(kp);
            short8 k1 = *(const short8*)(kp + 8);
            short8 v0 = *(const short8*)(vp);
            short8 v1 = *(const short8*)(vp + 8);
            uint4e ku = __builtin_bit_cast(uint4e, k0);
            uint2 u01 = {ku.x, ku.y}, u23 = {ku.z, ku.w};
            *(uint2*)&SM[0][srow][sseg * 16]     = u01;
            *(uint2*)&SM[0][srow][sseg * 16 + 4] = u23;
            ku = __builtin_bit_cast(uint4e, k1);
            u01.x = ku.x; u01.y = ku.y; u23.x = ku.z; u23.y = ku.w;
            *(uint2*)&SM[0][srow][sseg * 16 + 8]  = u01;
            *(uint2*)&SM[0][srow][sseg * 16 + 12] = u23;
            #pragma unroll
            for (int j = 0; j < 8; ++j) SM[1][sseg * 16 + j][srow]     = (unsigned short)v0[j];
            #pragma unroll
            for (int j = 0; j < 8; ++j) SM[1][sseg * 16 + 8 + j][srow] = (unsigned short)v1[j];
        }
        __syncthreads();

        const bool active = bottom ? (kb <= wq + 31) : true;
        if (active) {
            f32x16 s0 = fzero16(), s1 = fzero16();
            #pragma unroll
            for (int c = 0; c < 4; ++c) {
                const int off = c * 16 + hi * 8;
                uint2 a0 = *(const uint2*)&SM[0][l31][off];
                uint2 a1 = *(const uint2*)&SM[0][l31][off + 4];
                uint2 b0 = *(const uint2*)&SM[0][32 + l31][off];
                uint2 b1 = *(const uint2*)&SM[0][32 + l31][off + 4];
                s0 = __builtin_amdgcn_mfma_f32_32x32x16_bf16(
                        mk8(a0.x, a0.y, a1.x, a1.y), fq[c], s0, 0, 0, 0);
                s1 = __builtin_amdgcn_mfma_f32_32x32x16_bf16(
                        mk8(b0.x, b0.y, b1.x, b1.y), fq[c], s1, 0, 0, 0);
            }
            if (bottom && (kb + KVT - 1 > wq)) {
                const int qg = wq + l31;
                #pragma unroll
                for (int r = 0; r < 16; ++r) {
                    const int kk = (r & 3) + 8 * (r >> 2) + 4 * hi;
                    if (kb + kk > qg)      s0[r] = -1e30f;
                    if (kb + 32 + kk > qg) s1[r] = -1e30f;
                }
            }
            float pm = s0[0];
            #pragma unroll
            for (int r = 1; r < 16; ++r) pm = fmaxf(pm, s0[r]);
            #pragma unroll
            for (int r = 0; r < 16; ++r) pm = fmaxf(pm, s1[r]);
            pm = fmaxf(pm, __shfl_xor(pm, 32));
            const float mnew = fmaxf(mrun, pm);
            const float corr = __expf(mrun - mnew);
            float rs = 0.f;
            #pragma unroll
            for (int r = 0; r < 16; ++r) { s0[r] = __expf(s0[r] - mnew); rs += s0[r]; }
            #pragma unroll
            for (int r = 0; r < 16; ++r) { s1[r] = __expf(s1[r] - mnew); rs += s1[r]; }
            rs += __shfl_xor(rs, 32);
            lrun = lrun * corr + rs;
            mrun = mnew;
            #pragma unroll
            for (int i = 0; i < 16; ++i) { o0[i] *= corr; o1[i] *= corr; }
            #pragma unroll
            for (int kc = 0; kc < 4; ++kc) {
                const f32x16 src = (kc < 2) ? s0 : s1;
                const int rbase = (kc & 1) * 8;
                unsigned A01 = pkbf16(src[rbase + 0], src[rbase + 1]);
                unsigned A23 = pkbf16(src[rbase + 2], src[rbase + 3]);
                unsigned A45 = pkbf16(src[rbase + 4], src[rbase + 5]);
                unsigned A67 = pkbf16(src[rbase + 6], src[rbase + 7]);
                unsigned s01 = (unsigned)__shfl_xor((int)A01, 32);
                unsigned s23 = (unsigned)__shfl_xor((int)A23, 32);
                unsigned s45 = (unsigned)__shfl_xor((int)A45, 32);
                unsigned s67 = (unsigned)__shfl_xor((int)A67, 32);
                short8 fp = hi ? mk8(s45, s67, A45, A67)
                               : mk8(A01, A23, s01, s23);
                const int voff = kc * 16 + hi * 8;
                uint2 va0 = *(const uint2*)&SM[1][l31][voff];
                uint2 va1 = *(const uint2*)&SM[1][l31][voff + 4];
                uint2 vb0 = *(const uint2*)&SM[1][32 + l31][voff];
                uint2 vb1 = *(const uint2*)&SM[1][32 + l31][voff + 4];
                o0 = __builtin_amdgcn_mfma_f32_32x32x16_bf16(
                        mk8(va0.x, va0.y, va1.x, va1.y), fp, o0, 0, 0, 0);
                o1 = __builtin_amdgcn_mfma_f32_32x32x16_bf16(
                        mk8(vb0.x, vb0.y, vb1.x, vb1.y), fp, o1, 0, 0, 0);
            }
        }
        __syncthreads();
    }

    // epilogue: normalize, bounce O^T (bf16) through LDS, coalesced store
    const float inv = 1.f / lrun;
    unsigned short* obuf = (unsigned short*)&SM[0][0][0];  // [2][32][72] shorts
    for (int round = 0; round < 2; ++round) {
        if ((w >> 1) == round) {
            unsigned short* reg = obuf + (w & 1) * 2304 + (size_t)l31 * 72;
            #pragma unroll
            for (int r = 0; r < 16; ++r) {
                const int dd = (r & 3) + 8 * (r >> 2) + 4 * hi;
                reg[dd]      = f2bf(o0[r] * inv);
                reg[dd + 32] = f2bf(o1[r] * inv);
            }
        }
        __syncthreads();
        {
            const int row = t & 63, seg = t >> 6;
            const unsigned short* src = obuf + (row >> 5) * 2304 + (row & 31) * 72 + seg * 16;
            short8 y0 = *(const short8*)(src);
            short8 y1 = *(const short8*)(src + 8);
            unsigned short* dst = Og + (rb0 + qb + round * 64 + row) * DM + hd + seg * 16;
            *(short8*)(dst)     = y0;
            *(short8*)(dst + 8) = y1;
        }
        __syncthreads();
    }
}

// ---------------------------------------------------------------------------
extern "C" void kernel_launch(void* const* d_in, const int* in_sizes, int n_in,
                              void* d_out, int out_size, void* d_ws, size_t ws_size,
                              hipStream_t stream)
{
    const float* x  = (const float*)d_in[0];
    const float* Wq = (const float*)d_in[1];
    const float* bq = (const float*)d_in[2];
    const float* Wk = (const float*)d_in[3];
    const float* bk = (const float*)d_in[4];
    const float* Wv = (const float*)d_in[5];
    const float* bv = (const float*)d_in[6];
    const float* Wo = (const float*)d_in[7];
    float* out = (float*)d_out;

    char* ws = (char*)d_ws;
    const size_t szA = (size_t)MROWS * DM * 2;   // 8.39 MB (bf16 act)
    const size_t szW = (size_t)DM * DM * 2;      // 2.10 MB (bf16 weight)
    unsigned short* xb  = (unsigned short*)(ws);
    unsigned short* wqT = (unsigned short*)(ws + szA);
    unsigned short* wkT = (unsigned short*)(ws + szA + szW);
    unsigned short* wvT = (unsigned short*)(ws + szA + 2 * szW);
    unsigned short* woT = (unsigned short*)(ws + szA + 3 * szW);
    unsigned short* qb_ = (unsigned short*)(ws + szA + 4 * szW);
    unsigned short* kb_ = (unsigned short*)(ws + 2 * szA + 4 * szW);
    unsigned short* vb_ = (unsigned short*)(ws + 3 * szA + 4 * szW);
    unsigned short* ab_ = (unsigned short*)(ws + 4 * szA + 4 * szW);

    cvt_x<<<dim3(MROWS * DM / 8 / 256), 256, 0, stream>>>(x, xb, MROWS * DM / 8);
    dim3 wg(16, 16);
    cvt_wT<<<wg, 256, 0, stream>>>(Wq, wqT, DM, DM);
    cvt_wT<<<wg, 256, 0, stream>>>(Wk, wkT, DM, DM);
    cvt_wT<<<wg, 256, 0, stream>>>(Wv, wvT, DM, DM);
    cvt_wT<<<wg, 256, 0, stream>>>(Wo, woT, DM, DM);

    dim3 gg(DM / 128, MROWS / 128);  // (8, 32)
    gemm_bf16<<<gg, 256, 0, stream>>>(xb, wqT, bq, qb_, MROWS, DM, DM, 0.125f, 1);
    gemm_bf16<<<gg, 256, 0, stream>>>(xb, wkT, bk, kb_, MROWS, DM, DM, 1.0f, 1);
    gemm_bf16<<<gg, 256, 0, stream>>>(xb, wvT, bv, vb_, MROWS, DM, DM, 1.0f, 1);

    attn_mfma<<<dim3(16, 32), 256, 0, stream>>>(qb_, kb_, vb_, ab_);

    gemm_bf16<<<gg, 256, 0, stream>>>(ab_, woT, nullptr, out, MROWS, DM, DM, 1.0f, 0);
}

// Round 4
// 150.134 us; speedup vs baseline: 7.6601x; 1.3169x over previous
//
#include <hip/hip_runtime.h>
#include <hip/hip_bf16.h>

#define NH 16
#define DH 64
#define DM 1024
#define NC 2048
#define MROWS 4096
#define QB 128
#define KVT 64

typedef __attribute__((ext_vector_type(8))) short short8;
typedef __attribute__((ext_vector_type(4))) float f32x4;
typedef __attribute__((ext_vector_type(16))) float f32x16;
typedef __attribute__((ext_vector_type(4))) unsigned int uint4e;

__device__ __forceinline__ unsigned pkbf16(float a, float b) {
    unsigned r;
    asm("v_cvt_pk_bf16_f32 %0, %1, %2" : "=v"(r) : "v"(a), "v"(b));
    return r;
}
__device__ __forceinline__ unsigned short f2bf(float x) {
    return (unsigned short)(pkbf16(x, x) & 0xffffu);
}
__device__ __forceinline__ f32x16 fzero16() {
    f32x16 r;
    #pragma unroll
    for (int i = 0; i < 16; ++i) r[i] = 0.f;
    return r;
}
__device__ __forceinline__ short8 mk8(unsigned w0, unsigned w1, unsigned w2, unsigned w3) {
    uint4e u = {w0, w1, w2, w3};
    return __builtin_bit_cast(short8, u);
}

// ---------------------------------------------------------------------------
// fp32 -> bf16 elementwise convert (8 elems/thread)
// ---------------------------------------------------------------------------
__global__ __launch_bounds__(256) void cvt_x(const float* __restrict__ in,
                                             unsigned short* __restrict__ out, int n8)
{
    int i = blockIdx.x * 256 + threadIdx.x;
    if (i >= n8) return;
    const float4 a = ((const float4*)in)[i * 2];
    const float4 b = ((const float4*)in)[i * 2 + 1];
    uint4e u = {pkbf16(a.x, a.y), pkbf16(a.z, a.w), pkbf16(b.x, b.y), pkbf16(b.z, b.w)};
    ((uint4e*)out)[i] = u;
}

// ---------------------------------------------------------------------------
// W[K][N] fp32 -> Wt[N][K] bf16 (transpose + convert), 64x64 tiles
// ---------------------------------------------------------------------------
__global__ __launch_bounds__(256) void cvt_wT(const float* __restrict__ W,
                                              unsigned short* __restrict__ Wt,
                                              int Kd, int Nd)
{
    __shared__ unsigned short T[64][72];
    const int t = threadIdx.x;
    const int r = t >> 2, s = t & 3;
    const int bi = blockIdx.y;
    const int bj = blockIdx.x;
    const float* src = W + (size_t)(bi * 64 + r) * Nd + bj * 64 + s * 16;
    float4 f0 = ((const float4*)src)[0];
    float4 f1 = ((const float4*)src)[1];
    float4 f2 = ((const float4*)src)[2];
    float4 f3 = ((const float4*)src)[3];
    uint2 u;
    u.x = pkbf16(f0.x, f0.y); u.y = pkbf16(f0.z, f0.w); *(uint2*)&T[r][s * 16]      = u;
    u.x = pkbf16(f1.x, f1.y); u.y = pkbf16(f1.z, f1.w); *(uint2*)&T[r][s * 16 + 4]  = u;
    u.x = pkbf16(f2.x, f2.y); u.y = pkbf16(f2.z, f2.w); *(uint2*)&T[r][s * 16 + 8]  = u;
    u.x = pkbf16(f3.x, f3.y); u.y = pkbf16(f3.z, f3.w); *(uint2*)&T[r][s * 16 + 12] = u;
    __syncthreads();
    unsigned short vals[16];
    #pragma unroll
    for (int j = 0; j < 16; ++j) vals[j] = T[s * 16 + j][r];
    unsigned short* dst = Wt + (size_t)(bj * 64 + r) * Kd + bi * 64 + s * 16;
    *(short8*)(dst)     = *(short8*)&vals[0];
    *(short8*)(dst + 8) = *(short8*)&vals[8];
}

// ---------------------------------------------------------------------------
// Fused QKV projection: [4096,1024] @ WqkvT[3072,1024]^T. 128x128 tile, BK=32,
// 4 waves (2x2), reg-prefetch double-stage. Epilogue: per-segment bias/scale,
// bf16 out into q/k/v buffers (contiguous, seg = n0>>10). Q pre-scaled 0.125.
// ---------------------------------------------------------------------------
__global__ __launch_bounds__(256) void gemm_qkv(const unsigned short* __restrict__ A,
                                                const unsigned short* __restrict__ Bt,
                                                const float* __restrict__ bq,
                                                const float* __restrict__ bk,
                                                const float* __restrict__ bv,
                                                unsigned short* __restrict__ Out)
{
    __shared__ unsigned short As[128 * 40];
    __shared__ unsigned short Bs[128 * 40];
    const int t  = threadIdx.x;
    const int w  = t >> 6, l = t & 63;
    const int wr = w >> 1, wc = w & 1;
    const int m0 = blockIdx.y << 7;
    const int n0 = blockIdx.x << 7;
    const int r0 = t >> 2, ch = t & 3;

    f32x4 acc[4][4] = {};
    short8 ra[2], rb[2];
    #pragma unroll
    for (int j = 0; j < 2; ++j) {
        ra[j] = *(const short8*)(A  + (size_t)(m0 + r0 + j * 64) * DM + ch * 8);
        rb[j] = *(const short8*)(Bt + (size_t)(n0 + r0 + j * 64) * DM + ch * 8);
    }
    const int nkt = DM >> 5;
    for (int kt = 0; kt < nkt; ++kt) {
        #pragma unroll
        for (int j = 0; j < 2; ++j) {
            *(short8*)&As[(r0 + j * 64) * 40 + ch * 8] = ra[j];
            *(short8*)&Bs[(r0 + j * 64) * 40 + ch * 8] = rb[j];
        }
        __syncthreads();
        if (kt + 1 < nkt) {
            const int ko = (kt + 1) << 5;
            #pragma unroll
            for (int j = 0; j < 2; ++j) {
                ra[j] = *(const short8*)(A  + (size_t)(m0 + r0 + j * 64) * DM + ko + ch * 8);
                rb[j] = *(const short8*)(Bt + (size_t)(n0 + r0 + j * 64) * DM + ko + ch * 8);
            }
        }
        short8 af[4], bf_[4];
        #pragma unroll
        for (int mi = 0; mi < 4; ++mi)
            af[mi] = *(short8*)&As[(wr * 64 + mi * 16 + (l & 15)) * 40 + (l >> 4) * 8];
        #pragma unroll
        for (int ni = 0; ni < 4; ++ni)
            bf_[ni] = *(short8*)&Bs[(wc * 64 + ni * 16 + (l & 15)) * 40 + (l >> 4) * 8];
        #pragma unroll
        for (int mi = 0; mi < 4; ++mi)
            #pragma unroll
            for (int ni = 0; ni < 4; ++ni)
                acc[mi][ni] = __builtin_amdgcn_mfma_f32_16x16x32_bf16(
                                  af[mi], bf_[ni], acc[mi][ni], 0, 0, 0);
        __syncthreads();
    }

    const int seg = n0 >> 10;
    const float* bias = (seg == 0) ? bq : (seg == 1) ? bk : bv;
    const float scale = (seg == 0) ? 0.125f : 1.0f;
    unsigned short* C = Out + (size_t)seg * MROWS * DM;
    const int ncol0 = (n0 & 1023) + wc * 64;
    float bvv[4];
    #pragma unroll
    for (int ni = 0; ni < 4; ++ni)
        bvv[ni] = bias[ncol0 + ni * 16 + (l & 15)];
    #pragma unroll
    for (int mi = 0; mi < 4; ++mi)
        #pragma unroll
        for (int ni = 0; ni < 4; ++ni) {
            const int gcol = ncol0 + ni * 16 + (l & 15);
            #pragma unroll
            for (int r = 0; r < 4; ++r) {
                const int grow = m0 + wr * 64 + mi * 16 + (l >> 4) * 4 + r;
                C[(size_t)grow * DM + gcol] = f2bf((acc[mi][ni][r] + bvv[ni]) * scale);
            }
        }
}

// ---------------------------------------------------------------------------
// Output projection: [4096,1024] @ WoT[1024,1024]^T -> fp32. 64x128 tile
// (512 blocks = 2/CU), 4 waves (2x2), wave-tile 32x64, reg-prefetch.
// ---------------------------------------------------------------------------
__global__ __launch_bounds__(256) void gemm_wo(const unsigned short* __restrict__ A,
                                               const unsigned short* __restrict__ Bt,
                                               float* __restrict__ C)
{
    __shared__ unsigned short As[64 * 40];
    __shared__ unsigned short Bs[128 * 40];
    const int t = threadIdx.x, w = t >> 6, l = t & 63;
    const int wr = w >> 1, wc = w & 1;
    const int m0 = blockIdx.y << 6;
    const int n0 = blockIdx.x << 7;
    const int ar = t >> 2, ac = t & 3;
    const int brr = t >> 1, bc = t & 1;

    f32x4 acc[2][4] = {};
    short8 ra, rb0, rb1;
    ra  = *(const short8*)(A  + (size_t)(m0 + ar) * DM + ac * 8);
    rb0 = *(const short8*)(Bt + (size_t)(n0 + brr) * DM + bc * 16);
    rb1 = *(const short8*)(Bt + (size_t)(n0 + brr) * DM + bc * 16 + 8);
    const int nkt = DM >> 5;
    for (int kt = 0; kt < nkt; ++kt) {
        *(short8*)&As[ar * 40 + ac * 8] = ra;
        *(short8*)&Bs[brr * 40 + bc * 16]     = rb0;
        *(short8*)&Bs[brr * 40 + bc * 16 + 8] = rb1;
        __syncthreads();
        if (kt + 1 < nkt) {
            const int ko = (kt + 1) << 5;
            ra  = *(const short8*)(A  + (size_t)(m0 + ar) * DM + ko + ac * 8);
            rb0 = *(const short8*)(Bt + (size_t)(n0 + brr) * DM + ko + bc * 16);
            rb1 = *(const short8*)(Bt + (size_t)(n0 + brr) * DM + ko + bc * 16 + 8);
        }
        short8 af[2], bf_[4];
        #pragma unroll
        for (int mi = 0; mi < 2; ++mi)
            af[mi] = *(short8*)&As[(wr * 32 + mi * 16 + (l & 15)) * 40 + (l >> 4) * 8];
        #pragma unroll
        for (int ni = 0; ni < 4; ++ni)
            bf_[ni] = *(short8*)&Bs[(wc * 64 + ni * 16 + (l & 15)) * 40 + (l >> 4) * 8];
        #pragma unroll
        for (int mi = 0; mi < 2; ++mi)
            #pragma unroll
            for (int ni = 0; ni < 4; ++ni)
                acc[mi][ni] = __builtin_amdgcn_mfma_f32_16x16x32_bf16(
                                  af[mi], bf_[ni], acc[mi][ni], 0, 0, 0);
        __syncthreads();
    }
    #pragma unroll
    for (int mi = 0; mi < 2; ++mi)
        #pragma unroll
        for (int ni = 0; ni < 4; ++ni) {
            const int gcol = n0 + wc * 64 + ni * 16 + (l & 15);
            #pragma unroll
            for (int r = 0; r < 4; ++r) {
                const int grow = m0 + wr * 32 + mi * 16 + (l >> 4) * 4 + r;
                C[(size_t)grow * DM + gcol] = acc[mi][ni][r];
            }
        }
}

// ---------------------------------------------------------------------------
// bf16-MFMA flash attention (R3 math, new schedule):
//  - double-buffered LDS + register prefetch of next K/V tile (T14)
//  - XCD-chunked block swizzle: each XCD owns 4 heads x 16 q-tiles (T1)
//  - qt-flip on the second block wave per CU for causal load balance
// ---------------------------------------------------------------------------
__global__ __launch_bounds__(256) void attn_mfma(const unsigned short* __restrict__ Qg,
                                                 const unsigned short* __restrict__ Kg,
                                                 const unsigned short* __restrict__ Vg,
                                                 unsigned short* __restrict__ Og)
{
    __shared__ unsigned short Ks[2][64][68];
    __shared__ unsigned short Vt[2][64][68];
    const int t   = threadIdx.x;
    const int w   = t >> 6;
    const int l   = t & 63;
    const int l31 = l & 31;
    const int hi  = l >> 5;

    // XCD-chunked swizzle (512 blocks, 8 XCDs, round-robin dispatch assumed)
    const int f   = blockIdx.x;
    const int xcd = f & 7;
    const int pos = f >> 3;                 // 0..63
    const int bh  = xcd * 4 + (pos >> 4);   // 4 heads per XCD
    int qt = pos & 15;
    if (pos & 32) qt = 15 - qt;             // balance long/short causal blocks
    const int b = bh >> 4;
    const int h = bh & 15;

    const int qb = qt * QB;
    const int wq = qb + w * 32;
    const size_t rb0 = (size_t)b * NC;
    const int hd = h * DH;

    const unsigned short* qp = Qg + (rb0 + wq + l31) * DM + hd + hi * 8;
    short8 fq[4];
    #pragma unroll
    for (int c = 0; c < 4; ++c)
        fq[c] = *(const short8*)(qp + c * 16);

    f32x16 o0 = fzero16(), o1 = fzero16();
    float mrun = -1e30f, lrun = 0.f;
    const bool bottom = (qb >= NC / 2);
    const int nkv = bottom ? (2 * qt + 2) : 16;
    const int srow = t & 63;
    const int sseg = t >> 6;

    short8 kr0, kr1, vr0, vr1;
    auto loadKV = [&](int kbase) {
        const unsigned short* kp = Kg + (rb0 + kbase + srow) * DM + hd + sseg * 16;
        const unsigned short* vp = Vg + (rb0 + kbase + srow) * DM + hd + sseg * 16;
        kr0 = *(const short8*)(kp);
        kr1 = *(const short8*)(kp + 8);
        vr0 = *(const short8*)(vp);
        vr1 = *(const short8*)(vp + 8);
    };
    auto writeKV = [&](int bufi) {
        uint4e ku = __builtin_bit_cast(uint4e, kr0);
        uint2 u01; u01.x = ku.x; u01.y = ku.y;
        uint2 u23; u23.x = ku.z; u23.y = ku.w;
        *(uint2*)&Ks[bufi][srow][sseg * 16]     = u01;
        *(uint2*)&Ks[bufi][srow][sseg * 16 + 4] = u23;
        ku = __builtin_bit_cast(uint4e, kr1);
        u01.x = ku.x; u01.y = ku.y; u23.x = ku.z; u23.y = ku.w;
        *(uint2*)&Ks[bufi][srow][sseg * 16 + 8]  = u01;
        *(uint2*)&Ks[bufi][srow][sseg * 16 + 12] = u23;
        #pragma unroll
        for (int j = 0; j < 8; ++j) Vt[bufi][sseg * 16 + j][srow]     = (unsigned short)vr0[j];
        #pragma unroll
        for (int j = 0; j < 8; ++j) Vt[bufi][sseg * 16 + 8 + j][srow] = (unsigned short)vr1[j];
    };

    loadKV(0);
    writeKV(0);

    for (int it = 0; it < nkv; ++it) {
        __syncthreads();   // buf[it&1] visible; prior reads of buf[(it+1)&1] done
        const int kb = it * KVT;
        const int cur = it & 1;
        const bool havenext = (it + 1 < nkv);
        if (havenext) loadKV((it + 1) * KVT);   // global loads overlap compute

        const bool active = bottom ? (kb <= wq + 31) : true;
        if (active) {
            f32x16 s0 = fzero16(), s1 = fzero16();
            #pragma unroll
            for (int c = 0; c < 4; ++c) {
                const int off = c * 16 + hi * 8;
                uint2 a0 = *(const uint2*)&Ks[cur][l31][off];
                uint2 a1 = *(const uint2*)&Ks[cur][l31][off + 4];
                uint2 b0 = *(const uint2*)&Ks[cur][32 + l31][off];
                uint2 b1 = *(const uint2*)&Ks[cur][32 + l31][off + 4];
                s0 = __builtin_amdgcn_mfma_f32_32x32x16_bf16(
                        mk8(a0.x, a0.y, a1.x, a1.y), fq[c], s0, 0, 0, 0);
                s1 = __builtin_amdgcn_mfma_f32_32x32x16_bf16(
                        mk8(b0.x, b0.y, b1.x, b1.y), fq[c], s1, 0, 0, 0);
            }
            if (bottom && (kb + KVT - 1 > wq)) {
                const int qg = wq + l31;
                #pragma unroll
                for (int r = 0; r < 16; ++r) {
                    const int kk = (r & 3) + 8 * (r >> 2) + 4 * hi;
                    if (kb + kk > qg)      s0[r] = -1e30f;
                    if (kb + 32 + kk > qg) s1[r] = -1e30f;
                }
            }
            float pm = s0[0];
            #pragma unroll
            for (int r = 1; r < 16; ++r) pm = fmaxf(pm, s0[r]);
            #pragma unroll
            for (int r = 0; r < 16; ++r) pm = fmaxf(pm, s1[r]);
            pm = fmaxf(pm, __shfl_xor(pm, 32));
            const float mnew = fmaxf(mrun, pm);
            const float corr = __expf(mrun - mnew);
            float rs = 0.f;
            #pragma unroll
            for (int r = 0; r < 16; ++r) { s0[r] = __expf(s0[r] - mnew); rs += s0[r]; }
            #pragma unroll
            for (int r = 0; r < 16; ++r) { s1[r] = __expf(s1[r] - mnew); rs += s1[r]; }
            rs += __shfl_xor(rs, 32);
            lrun = lrun * corr + rs;
            mrun = mnew;
            #pragma unroll
            for (int i = 0; i < 16; ++i) { o0[i] *= corr; o1[i] *= corr; }
            #pragma unroll
            for (int kc = 0; kc < 4; ++kc) {
                const f32x16 src = (kc < 2) ? s0 : s1;
                const int rbase = (kc & 1) * 8;
                unsigned A01 = pkbf16(src[rbase + 0], src[rbase + 1]);
                unsigned A23 = pkbf16(src[rbase + 2], src[rbase + 3]);
                unsigned A45 = pkbf16(src[rbase + 4], src[rbase + 5]);
                unsigned A67 = pkbf16(src[rbase + 6], src[rbase + 7]);
                unsigned s01 = (unsigned)__shfl_xor((int)A01, 32);
                unsigned s23 = (unsigned)__shfl_xor((int)A23, 32);
                unsigned s45 = (unsigned)__shfl_xor((int)A45, 32);
                unsigned s67 = (unsigned)__shfl_xor((int)A67, 32);
                short8 fp = hi ? mk8(s45, s67, A45, A67)
                               : mk8(A01, A23, s01, s23);
                const int voff = kc * 16 + hi * 8;
                uint2 va0 = *(const uint2*)&Vt[cur][l31][voff];
                uint2 va1 = *(const uint2*)&Vt[cur][l31][voff + 4];
                uint2 vb0 = *(const uint2*)&Vt[cur][32 + l31][voff];
                uint2 vb1 = *(const uint2*)&Vt[cur][32 + l31][voff + 4];
                o0 = __builtin_amdgcn_mfma_f32_32x32x16_bf16(
                        mk8(va0.x, va0.y, va1.x, va1.y), fp, o0, 0, 0, 0);
                o1 = __builtin_amdgcn_mfma_f32_32x32x16_bf16(
                        mk8(vb0.x, vb0.y, vb1.x, vb1.y), fp, o1, 0, 0, 0);
            }
        }
        if (havenext) writeKV((it + 1) & 1);   // vmcnt drain lands here, post-compute
    }
    __syncthreads();   // all compute done before reusing Ks as obuf

    const float inv = 1.f / lrun;
    unsigned short* obuf = (unsigned short*)&Ks[0][0][0];
    for (int round = 0; round < 2; ++round) {
        if ((w >> 1) == round) {
            unsigned short* reg = obuf + (w & 1) * 2304 + (size_t)l31 * 72;
            #pragma unroll
            for (int r = 0; r < 16; ++r) {
                const int dd = (r & 3) + 8 * (r >> 2) + 4 * hi;
                reg[dd]      = f2bf(o0[r] * inv);
                reg[dd + 32] = f2bf(o1[r] * inv);
            }
        }
        __syncthreads();
        {
            const int row = t & 63, seg = t >> 6;
            const unsigned short* src = obuf + (row >> 5) * 2304 + (row & 31) * 72 + seg * 16;
            short8 y0 = *(const short8*)(src);
            short8 y1 = *(const short8*)(src + 8);
            unsigned short* dst = Og + (rb0 + qb + round * 64 + row) * DM + hd + seg * 16;
            *(short8*)(dst)     = y0;
            *(short8*)(dst + 8) = y1;
        }
        __syncthreads();
    }
}

// ---------------------------------------------------------------------------
extern "C" void kernel_launch(void* const* d_in, const int* in_sizes, int n_in,
                              void* d_out, int out_size, void* d_ws, size_t ws_size,
                              hipStream_t stream)
{
    const float* x  = (const float*)d_in[0];
    const float* Wq = (const float*)d_in[1];
    const float* bq = (const float*)d_in[2];
    const float* Wk = (const float*)d_in[3];
    const float* bk = (const float*)d_in[4];
    const float* Wv = (const float*)d_in[5];
    const float* bv = (const float*)d_in[6];
    const float* Wo = (const float*)d_in[7];
    float* out = (float*)d_out;

    char* ws = (char*)d_ws;
    const size_t szA = (size_t)MROWS * DM * 2;   // 8.39 MB
    const size_t szW = (size_t)DM * DM * 2;      // 2.10 MB
    unsigned short* xb  = (unsigned short*)(ws);
    unsigned short* wqT = (unsigned short*)(ws + szA);            // wq/wk/wv/wo contiguous
    unsigned short* woT = (unsigned short*)(ws + szA + 3 * szW);
    unsigned short* qb_ = (unsigned short*)(ws + szA + 4 * szW);  // q/k/v contiguous
    unsigned short* kb_ = (unsigned short*)(ws + 2 * szA + 4 * szW);
    unsigned short* vb_ = (unsigned short*)(ws + 3 * szA + 4 * szW);
    unsigned short* ab_ = (unsigned short*)(ws + 4 * szA + 4 * szW);

    cvt_x<<<dim3(MROWS * DM / 8 / 256), 256, 0, stream>>>(x, xb, MROWS * DM / 8);
    dim3 wg(16, 16);
    cvt_wT<<<wg, 256, 0, stream>>>(Wq, wqT, DM, DM);
    cvt_wT<<<wg, 256, 0, stream>>>(Wk, wqT + (size_t)DM * DM, DM, DM);
    cvt_wT<<<wg, 256, 0, stream>>>(Wv, wqT + 2 * (size_t)DM * DM, DM, DM);
    cvt_wT<<<wg, 256, 0, stream>>>(Wo, woT, DM, DM);

    gemm_qkv<<<dim3(24, 32), 256, 0, stream>>>(xb, wqT, bq, bk, bv, qb_);
    attn_mfma<<<dim3(512), 256, 0, stream>>>(qb_, kb_, vb_, ab_);
    gemm_wo<<<dim3(8, 64), 256, 0, stream>>>(ab_, woT, out);
}

// Round 5
// 135.338 us; speedup vs baseline: 8.4976x; 1.1093x over previous
//
#include <hip/hip_runtime.h>
#include <hip/hip_bf16.h>

#define NH 16
#define DH 64
#define DM 1024
#define NC 2048
#define MROWS 4096
#define KVT 64

#define SCALE_Q 0.180336880f   // 0.125 * log2(e): softmax done in 2^x domain

typedef __attribute__((ext_vector_type(8))) short short8;
typedef __attribute__((ext_vector_type(4))) float f32x4;
typedef __attribute__((ext_vector_type(16))) float f32x16;
typedef __attribute__((ext_vector_type(4))) unsigned int uint4e;

__device__ __forceinline__ unsigned pkbf16(float a, float b) {
    unsigned r;
    asm("v_cvt_pk_bf16_f32 %0, %1, %2" : "=v"(r) : "v"(a), "v"(b));
    return r;
}
__device__ __forceinline__ unsigned short f2bf(float x) {
    return (unsigned short)(pkbf16(x, x) & 0xffffu);
}
__device__ __forceinline__ float exp2v(float x) {   // 2^x, v_exp_f32
    float r;
    asm("v_exp_f32 %0, %1" : "=v"(r) : "v"(x));
    return r;
}
__device__ __forceinline__ f32x16 fzero16() {
    f32x16 r;
    #pragma unroll
    for (int i = 0; i < 16; ++i) r[i] = 0.f;
    return r;
}
__device__ __forceinline__ short8 mk8(unsigned w0, unsigned w1, unsigned w2, unsigned w3) {
    uint4e u = {w0, w1, w2, w3};
    return __builtin_bit_cast(short8, u);
}
// async global->LDS, 16B per lane; lds dest must be wave-uniform base (+lane*16 by HW)
__device__ __forceinline__ void gload16(const unsigned short* g, unsigned short* l) {
    __builtin_amdgcn_global_load_lds(
        (const __attribute__((address_space(1))) void*)g,
        (__attribute__((address_space(3))) void*)l, 16, 0, 0);
}

// ---------------------------------------------------------------------------
// fp32 -> bf16 elementwise convert (8 elems/thread)
// ---------------------------------------------------------------------------
__global__ __launch_bounds__(256) void cvt_x(const float* __restrict__ in,
                                             unsigned short* __restrict__ out, int n8)
{
    int i = blockIdx.x * 256 + threadIdx.x;
    if (i >= n8) return;
    const float4 a = ((const float4*)in)[i * 2];
    const float4 b = ((const float4*)in)[i * 2 + 1];
    uint4e u = {pkbf16(a.x, a.y), pkbf16(a.z, a.w), pkbf16(b.x, b.y), pkbf16(b.z, b.w)};
    ((uint4e*)out)[i] = u;
}

// ---------------------------------------------------------------------------
// All 4 weights: W[K][N] fp32 -> Wt[N][K] bf16, fused (blockIdx.z = which W)
// ---------------------------------------------------------------------------
__global__ __launch_bounds__(256) void cvt_w4(const float* __restrict__ W0,
                                              const float* __restrict__ W1,
                                              const float* __restrict__ W2,
                                              const float* __restrict__ W3,
                                              unsigned short* __restrict__ Wt4)
{
    __shared__ unsigned short T[64][72];
    const int z = blockIdx.z;
    const float* W = (z == 0) ? W0 : (z == 1) ? W1 : (z == 2) ? W2 : W3;
    unsigned short* Wt = Wt4 + (size_t)z * DM * DM;
    const int t = threadIdx.x;
    const int r = t >> 2, s = t & 3;
    const int bi = blockIdx.y;
    const int bj = blockIdx.x;
    const float* src = W + (size_t)(bi * 64 + r) * DM + bj * 64 + s * 16;
    float4 f0 = ((const float4*)src)[0];
    float4 f1 = ((const float4*)src)[1];
    float4 f2 = ((const float4*)src)[2];
    float4 f3 = ((const float4*)src)[3];
    uint2 u;
    u.x = pkbf16(f0.x, f0.y); u.y = pkbf16(f0.z, f0.w); *(uint2*)&T[r][s * 16]      = u;
    u.x = pkbf16(f1.x, f1.y); u.y = pkbf16(f1.z, f1.w); *(uint2*)&T[r][s * 16 + 4]  = u;
    u.x = pkbf16(f2.x, f2.y); u.y = pkbf16(f2.z, f2.w); *(uint2*)&T[r][s * 16 + 8]  = u;
    u.x = pkbf16(f3.x, f3.y); u.y = pkbf16(f3.z, f3.w); *(uint2*)&T[r][s * 16 + 12] = u;
    __syncthreads();
    unsigned short vals[16];
    #pragma unroll
    for (int j = 0; j < 16; ++j) vals[j] = T[s * 16 + j][r];
    unsigned short* dst = Wt + (size_t)(bj * 64 + r) * DM + bi * 64 + s * 16;
    *(short8*)(dst)     = *(short8*)&vals[0];
    *(short8*)(dst + 8) = *(short8*)&vals[8];
}

// ---------------------------------------------------------------------------
// Fused QKV projection (m97 structure): 128x128 tile, BK=32, 4 waves,
// global_load_lds width-16 staging into LINEAR LDS [128][32] shorts.
// Q segment pre-scaled by SCALE_Q.
// ---------------------------------------------------------------------------
__global__ __launch_bounds__(256) void gemm_qkv(const unsigned short* __restrict__ A,
                                                const unsigned short* __restrict__ Bt,
                                                const float* __restrict__ bq,
                                                const float* __restrict__ bk,
                                                const float* __restrict__ bv,
                                                unsigned short* __restrict__ Out)
{
    __shared__ unsigned short As[128 * 32];
    __shared__ unsigned short Bs[128 * 32];
    const int t  = threadIdx.x;
    const int w  = t >> 6, l = t & 63;
    const int wr = w >> 1, wc = w & 1;
    const int m0 = blockIdx.y << 7;
    const int n0 = blockIdx.x << 7;

    f32x4 acc[4][4] = {};
    const int nkt = DM >> 5;
    for (int kt = 0; kt < nkt; ++kt) {
        #pragma unroll
        for (int j = 0; j < 2; ++j) {
            const int c0 = j * 256 + w * 64;          // wave-uniform chunk base
            const int cc = c0 + l;                    // per-lane chunk
            const int row = cc >> 2, qq = cc & 3;
            gload16(A  + (size_t)(m0 + row) * DM + kt * 32 + qq * 8, &As[c0 * 8]);
            gload16(Bt + (size_t)(n0 + row) * DM + kt * 32 + qq * 8, &Bs[c0 * 8]);
        }
        __syncthreads();
        short8 af[4], bf_[4];
        #pragma unroll
        for (int mi = 0; mi < 4; ++mi)
            af[mi] = *(short8*)&As[(wr * 64 + mi * 16 + (l & 15)) * 32 + (l >> 4) * 8];
        #pragma unroll
        for (int ni = 0; ni < 4; ++ni)
            bf_[ni] = *(short8*)&Bs[(wc * 64 + ni * 16 + (l & 15)) * 32 + (l >> 4) * 8];
        #pragma unroll
        for (int mi = 0; mi < 4; ++mi)
            #pragma unroll
            for (int ni = 0; ni < 4; ++ni)
                acc[mi][ni] = __builtin_amdgcn_mfma_f32_16x16x32_bf16(
                                  af[mi], bf_[ni], acc[mi][ni], 0, 0, 0);
        __syncthreads();
    }

    const int seg = n0 >> 10;
    const float* bias = (seg == 0) ? bq : (seg == 1) ? bk : bv;
    const float scale = (seg == 0) ? SCALE_Q : 1.0f;
    unsigned short* C = Out + (size_t)seg * MROWS * DM;
    const int ncol0 = (n0 & 1023) + wc * 64;
    float bvv[4];
    #pragma unroll
    for (int ni = 0; ni < 4; ++ni)
        bvv[ni] = bias[ncol0 + ni * 16 + (l & 15)];
    #pragma unroll
    for (int mi = 0; mi < 4; ++mi)
        #pragma unroll
        for (int ni = 0; ni < 4; ++ni) {
            const int gcol = ncol0 + ni * 16 + (l & 15);
            #pragma unroll
            for (int r = 0; r < 4; ++r) {
                const int grow = m0 + wr * 64 + mi * 16 + (l >> 4) * 4 + r;
                C[(size_t)grow * DM + gcol] = f2bf((acc[mi][ni][r] + bvv[ni]) * scale);
            }
        }
}

// ---------------------------------------------------------------------------
// Output projection: 64x128 tile, gload_lds staging, fp32 out.
// ---------------------------------------------------------------------------
__global__ __launch_bounds__(256) void gemm_wo(const unsigned short* __restrict__ A,
                                               const unsigned short* __restrict__ Bt,
                                               float* __restrict__ C)
{
    __shared__ unsigned short As[64 * 32];
    __shared__ unsigned short Bs[128 * 32];
    const int t = threadIdx.x, w = t >> 6, l = t & 63;
    const int wr = w >> 1, wc = w & 1;
    const int m0 = blockIdx.y << 6;
    const int n0 = blockIdx.x << 7;

    f32x4 acc[2][4] = {};
    const int nkt = DM >> 5;
    for (int kt = 0; kt < nkt; ++kt) {
        {
            const int c0 = w * 64;
            const int cc = c0 + l;
            const int row = cc >> 2, qq = cc & 3;
            gload16(A + (size_t)(m0 + row) * DM + kt * 32 + qq * 8, &As[c0 * 8]);
        }
        #pragma unroll
        for (int j = 0; j < 2; ++j) {
            const int c0 = j * 256 + w * 64;
            const int cc = c0 + l;
            const int row = cc >> 2, qq = cc & 3;
            gload16(Bt + (size_t)(n0 + row) * DM + kt * 32 + qq * 8, &Bs[c0 * 8]);
        }
        __syncthreads();
        short8 af[2], bf_[4];
        #pragma unroll
        for (int mi = 0; mi < 2; ++mi)
            af[mi] = *(short8*)&As[(wr * 32 + mi * 16 + (l & 15)) * 32 + (l >> 4) * 8];
        #pragma unroll
        for (int ni = 0; ni < 4; ++ni)
            bf_[ni] = *(short8*)&Bs[(wc * 64 + ni * 16 + (l & 15)) * 32 + (l >> 4) * 8];
        #pragma unroll
        for (int mi = 0; mi < 2; ++mi)
            #pragma unroll
            for (int ni = 0; ni < 4; ++ni)
                acc[mi][ni] = __builtin_amdgcn_mfma_f32_16x16x32_bf16(
                                  af[mi], bf_[ni], acc[mi][ni], 0, 0, 0);
        __syncthreads();
    }
    #pragma unroll
    for (int mi = 0; mi < 2; ++mi)
        #pragma unroll
        for (int ni = 0; ni < 4; ++ni) {
            const int gcol = n0 + wc * 64 + ni * 16 + (l & 15);
            #pragma unroll
            for (int r = 0; r < 4; ++r) {
                const int grow = m0 + wr * 32 + mi * 16 + (l >> 4) * 4 + r;
                C[(size_t)grow * DM + gcol] = acc[mi][ni][r];
            }
        }
}

// ---------------------------------------------------------------------------
// bf16-MFMA flash attention. QB=64, 2 waves / 128 threads -> 1024 blocks
// (4 independent blocks/CU). Softmax in 2^x domain (Q pre-scaled by log2e),
// max-tree reduction, T13 defer-rescale, dbuf + reg prefetch (T14),
// XCD-chunked swizzle (T1).
// ---------------------------------------------------------------------------
__global__ __launch_bounds__(128) void attn_mfma(const unsigned short* __restrict__ Qg,
                                                 const unsigned short* __restrict__ Kg,
                                                 const unsigned short* __restrict__ Vg,
                                                 unsigned short* __restrict__ Og)
{
    __shared__ unsigned short Ks[2][64][68];
    __shared__ unsigned short Vt[2][64][68];
    const int t   = threadIdx.x;
    const int w   = t >> 6;          // 0..1
    const int l   = t & 63;
    const int l31 = l & 31;
    const int hi  = l >> 5;

    // XCD-chunked swizzle: 1024 blocks, 8 XCDs -> 4 heads x 32 q-tiles each
    const int f   = blockIdx.x;
    const int xcd = f & 7;
    const int pos = f >> 3;               // 0..127
    const int bh  = xcd * 4 + (pos >> 5); // 4 (b,h) per XCD
    int qt = pos & 31;
    if ((pos >> 5) & 1) qt = 31 - qt;     // alternate direction for balance
    const int b = bh >> 4;
    const int h = bh & 15;

    const int qb = qt << 6;               // 64 q-rows per block
    const int wq = qb + w * 32;
    const size_t rb0 = (size_t)b * NC;
    const int hd = h * DH;

    const unsigned short* qp = Qg + (rb0 + wq + l31) * DM + hd + hi * 8;
    short8 fq[4];
    #pragma unroll
    for (int c = 0; c < 4; ++c)
        fq[c] = *(const short8*)(qp + c * 16);

    f32x16 o0 = fzero16(), o1 = fzero16();
    float mrun = -1e30f, lrun = 0.f;
    const bool bottom = (qb >= NC / 2);   // qt >= 16
    const int nkv = bottom ? (qt + 1) : 16;
    const int srow = t >> 1;              // 0..63
    const int sseg = t & 1;               // 32-short half

    short8 kr[4], vr[4];
    auto loadKV = [&](int kbase) {
        const unsigned short* kp = Kg + (rb0 + kbase + srow) * DM + hd + sseg * 32;
        const unsigned short* vp = Vg + (rb0 + kbase + srow) * DM + hd + sseg * 32;
        #pragma unroll
        for (int i = 0; i < 4; ++i) {
            kr[i] = *(const short8*)(kp + i * 8);
            vr[i] = *(const short8*)(vp + i * 8);
        }
    };
    auto writeKV = [&](int bufi) {
        #pragma unroll
        for (int i = 0; i < 4; ++i) {
            uint4e ku = __builtin_bit_cast(uint4e, kr[i]);
            uint2 u01; u01.x = ku.x; u01.y = ku.y;
            uint2 u23; u23.x = ku.z; u23.y = ku.w;
            *(uint2*)&Ks[bufi][srow][sseg * 32 + i * 8]     = u01;
            *(uint2*)&Ks[bufi][srow][sseg * 32 + i * 8 + 4] = u23;
            #pragma unroll
            for (int j = 0; j < 8; ++j)
                Vt[bufi][sseg * 32 + i * 8 + j][srow] = (unsigned short)vr[i][j];
        }
    };

    loadKV(0);
    writeKV(0);

    for (int it = 0; it < nkv; ++it) {
        __syncthreads();
        const int kb = it * KVT;
        const int cur = it & 1;
        const bool havenext = (it + 1 < nkv);
        if (havenext) loadKV((it + 1) * KVT);

        const bool active = bottom ? (kb <= wq + 31) : true;
        if (active) {
            f32x16 s0 = fzero16(), s1 = fzero16();
            #pragma unroll
            for (int c = 0; c < 4; ++c) {
                const int off = c * 16 + hi * 8;
                uint2 a0 = *(const uint2*)&Ks[cur][l31][off];
                uint2 a1 = *(const uint2*)&Ks[cur][l31][off + 4];
                uint2 b0 = *(const uint2*)&Ks[cur][32 + l31][off];
                uint2 b1 = *(const uint2*)&Ks[cur][32 + l31][off + 4];
                s0 = __builtin_amdgcn_mfma_f32_32x32x16_bf16(
                        mk8(a0.x, a0.y, a1.x, a1.y), fq[c], s0, 0, 0, 0);
                s1 = __builtin_amdgcn_mfma_f32_32x32x16_bf16(
                        mk8(b0.x, b0.y, b1.x, b1.y), fq[c], s1, 0, 0, 0);
            }
            if (bottom && (kb + KVT - 1 > wq)) {
                const int qg = wq + l31;
                #pragma unroll
                for (int r = 0; r < 16; ++r) {
                    const int kk = (r & 3) + 8 * (r >> 2) + 4 * hi;
                    if (kb + kk > qg)      s0[r] = -1e30f;
                    if (kb + 32 + kk > qg) s1[r] = -1e30f;
                }
            }
            // ---- max tree (parallel, v_max3-fusable) ----
            float tm[16];
            #pragma unroll
            for (int r = 0; r < 16; ++r) tm[r] = fmaxf(s0[r], s1[r]);
            #pragma unroll
            for (int st = 8; st > 0; st >>= 1)
                #pragma unroll
                for (int r = 0; r < 8; ++r)
                    if (r < st) tm[r] = fmaxf(tm[r], tm[r + st]);
            float pm = fmaxf(tm[0], __shfl_xor(tm[0], 32));
            // ---- T13 defer-rescale ----
            if (!__all(pm - mrun <= 8.f)) {
                const float mnew = fmaxf(mrun, pm);
                const float corr = exp2v(mrun - mnew);
                mrun = mnew;
                lrun *= corr;
                #pragma unroll
                for (int i = 0; i < 16; ++i) { o0[i] *= corr; o1[i] *= corr; }
            }
            float rs = 0.f;
            #pragma unroll
            for (int r = 0; r < 16; ++r) { s0[r] = exp2v(s0[r] - mrun); rs += s0[r]; }
            #pragma unroll
            for (int r = 0; r < 16; ++r) { s1[r] = exp2v(s1[r] - mrun); rs += s1[r]; }
            rs += __shfl_xor(rs, 32);
            lrun += rs;
            // ---- P -> bf16 B-frags, PV accumulate ----
            #pragma unroll
            for (int kc = 0; kc < 4; ++kc) {
                const f32x16 src = (kc < 2) ? s0 : s1;
                const int rbase = (kc & 1) * 8;
                unsigned A01 = pkbf16(src[rbase + 0], src[rbase + 1]);
                unsigned A23 = pkbf16(src[rbase + 2], src[rbase + 3]);
                unsigned A45 = pkbf16(src[rbase + 4], src[rbase + 5]);
                unsigned A67 = pkbf16(src[rbase + 6], src[rbase + 7]);
                unsigned s01 = (unsigned)__shfl_xor((int)A01, 32);
                unsigned s23 = (unsigned)__shfl_xor((int)A23, 32);
                unsigned s45 = (unsigned)__shfl_xor((int)A45, 32);
                unsigned s67 = (unsigned)__shfl_xor((int)A67, 32);
                short8 fp = hi ? mk8(s45, s67, A45, A67)
                               : mk8(A01, A23, s01, s23);
                const int voff = kc * 16 + hi * 8;
                uint2 va0 = *(const uint2*)&Vt[cur][l31][voff];
                uint2 va1 = *(const uint2*)&Vt[cur][l31][voff + 4];
                uint2 vb0 = *(const uint2*)&Vt[cur][32 + l31][voff];
                uint2 vb1 = *(const uint2*)&Vt[cur][32 + l31][voff + 4];
                o0 = __builtin_amdgcn_mfma_f32_32x32x16_bf16(
                        mk8(va0.x, va0.y, va1.x, va1.y), fp, o0, 0, 0, 0);
                o1 = __builtin_amdgcn_mfma_f32_32x32x16_bf16(
                        mk8(vb0.x, vb0.y, vb1.x, vb1.y), fp, o1, 0, 0, 0);
            }
        }
        if (havenext) writeKV((it + 1) & 1);
    }
    __syncthreads();

    // epilogue: normalize, bounce O^T (bf16) through LDS, coalesced store
    const float inv = 1.f / lrun;
    unsigned short* obuf = (unsigned short*)&Ks[0][0][0];  // [64][72] shorts
    {
        unsigned short* reg = obuf + (size_t)(w * 32 + l31) * 72;
        #pragma unroll
        for (int r = 0; r < 16; ++r) {
            const int dd = (r & 3) + 8 * (r >> 2) + 4 * hi;
            reg[dd]      = f2bf(o0[r] * inv);
            reg[dd + 32] = f2bf(o1[r] * inv);
        }
    }
    __syncthreads();
    {
        const int row = t >> 1, seg = t & 1;
        const unsigned short* src = obuf + (size_t)row * 72 + seg * 32;
        unsigned short* dst = Og + (rb0 + qb + row) * DM + hd + seg * 32;
        #pragma unroll
        for (int i = 0; i < 4; ++i)
            *(short8*)(dst + i * 8) = *(const short8*)(src + i * 8);
    }
}

// ---------------------------------------------------------------------------
extern "C" void kernel_launch(void* const* d_in, const int* in_sizes, int n_in,
                              void* d_out, int out_size, void* d_ws, size_t ws_size,
                              hipStream_t stream)
{
    const float* x  = (const float*)d_in[0];
    const float* Wq = (const float*)d_in[1];
    const float* bq = (const float*)d_in[2];
    const float* Wk = (const float*)d_in[3];
    const float* bk = (const float*)d_in[4];
    const float* Wv = (const float*)d_in[5];
    const float* bv = (const float*)d_in[6];
    const float* Wo = (const float*)d_in[7];
    float* out = (float*)d_out;

    char* ws = (char*)d_ws;
    const size_t szA = (size_t)MROWS * DM * 2;   // 8.39 MB
    const size_t szW = (size_t)DM * DM * 2;      // 2.10 MB
    unsigned short* xb  = (unsigned short*)(ws);
    unsigned short* wqT = (unsigned short*)(ws + szA);            // wq/wk/wv/wo contiguous
    unsigned short* woT = (unsigned short*)(ws + szA + 3 * szW);
    unsigned short* qb_ = (unsigned short*)(ws + szA + 4 * szW);  // q/k/v contiguous
    unsigned short* kb_ = (unsigned short*)(ws + 2 * szA + 4 * szW);
    unsigned short* vb_ = (unsigned short*)(ws + 3 * szA + 4 * szW);
    unsigned short* ab_ = (unsigned short*)(ws + 4 * szA + 4 * szW);

    cvt_x<<<dim3(MROWS * DM / 8 / 256), 256, 0, stream>>>(x, xb, MROWS * DM / 8);
    cvt_w4<<<dim3(16, 16, 4), 256, 0, stream>>>(Wq, Wk, Wv, Wo, wqT);

    gemm_qkv<<<dim3(24, 32), 256, 0, stream>>>(xb, wqT, bq, bk, bv, qb_);
    attn_mfma<<<dim3(1024), 128, 0, stream>>>(qb_, kb_, vb_, ab_);
    gemm_wo<<<dim3(8, 64), 256, 0, stream>>>(ab_, woT, out);
}